// Round 16
// baseline (166.052 us; speedup 1.0000x reference)
//
#include <hip/hip_runtime.h>

// Problem constants (B=1): inputs (N=32768, D=1024) f32, tag_to_token (T=128, N) f32,
// gat_mask (T, T) i32. Output (T, D) f32.
#define NTOK 32768
#define NTAG 128
#define DDIM 1024
#define TPB 32  // tokens per streaming block

// ws layout:
//   P   : 524288 B (unscaled per-tag sums)
//   cnt : 512 B
//   Wa  : 65536 B (128x128 matrix ping)
//   Wb  : 65536 B (128x128 matrix pong; ends as final A)

// ---------------------------------------------------------------------------
// Kernel 0 (k_zero): zero P and cnt (P receives atomics in k_fused).
// ---------------------------------------------------------------------------
__global__ __launch_bounds__(256) void k_zero(float* __restrict__ P,
                                              int* __restrict__ cnt) {
    const int gid = blockIdx.x * 256 + threadIdx.x;  // 32768 threads
    reinterpret_cast<float4*>(P)[gid] = make_float4(0.f, 0.f, 0.f, 0.f);
    if (gid < NTAG) cnt[gid] = 0;
}

// ---------------------------------------------------------------------------
// Kernel 1 (k_fused): block 0 = A-builder; blocks 1..1024 = tag-scan +
// segmented sum (byte-identical streaming logic to R8/R15, verified).
//
// A-builder (runs concurrently, hidden under the ~26us stream): builds the
// full triangular-recurrence matrix A = G0*G1*...*G7 (R12's verified math):
//   (a) RT16: 8 groups of 16 rows by in-group back-substitution
//       rt_j = gm_j masked outside (j, g0+16) + sum_{k>j in grp} gm_j[k]*rt_k
//   (b) 3 combine levels (S=16,32,64): lo rows get hi-span substituted,
//       hi rows copy through; ALL coefficients LDS-staged (R13's one-block
//       builder was slow only because co[] was re-read from global per-fma).
// deduce_child(gm) == gm for ANY input (reference inner loop provably no-op).
//
// Math fact (streamer): deduce_direct_string's temp[i][n] is 1 iff i is the
// LAST covering tag of n (for ANY 0/1 coverage), so the row-normalized t2t
// is one-hot per token / cnt[tag] -> the big matmul is a segmented sum.
// ---------------------------------------------------------------------------
__global__ __launch_bounds__(256, 1) void k_fused(const float* __restrict__ inp,
                                                  const float* __restrict__ t2t,
                                                  float* __restrict__ P,
                                                  int* __restrict__ cnt,
                                                  const int* __restrict__ gm,
                                                  float* __restrict__ Wa,
                                                  float* __restrict__ Wb) {
    __shared__ __align__(16) float smem[6144];  // 24 KB: co[4096] | hi[2048]
    __shared__ int part[8][TPB];
    __shared__ int tags[TPB];
    const int tid = threadIdx.x;

    if (blockIdx.x == 0) {
        // ================= A builder =================
        float* co = smem;         // combine coeffs (also rt[16][128] in (a))
        float* hi = smem + 4096;  // hi-row slice   (also gblk[16][16] in (a))

        // ---- (a) RT16 into Wa ----
        float* rt = co;
        float* gblk = hi;
        for (int g = 0; g < 8; ++g) {
            const int g0 = g * 16;
            gblk[tid] = (float)(gm[(g0 + (tid >> 4)) * NTAG + g0 + (tid & 15)] != 0);
            __syncthreads();
            for (int jj = 15; jj >= 0; --jj) {
                const int t = tid & 127;  // tids 128..255 duplicate (benign)
                const int j = g0 + jj;
                float acc = (t > j && t < g0 + 16)
                                ? 0.f
                                : (float)(gm[(g0 + jj) * NTAG + t] != 0);
                for (int k = jj + 1; k < 16; ++k)
                    acc += gblk[jj * 16 + k] * rt[k * 128 + t];
                rt[jj * 128 + t] = acc;
                __syncthreads();
            }
            for (int q = tid; q < 16 * 128; q += 256)
                Wa[(g0 + (q >> 7)) * NTAG + (q & 127)] = rt[q];
            __syncthreads();
        }

        // ---- (b) combine levels: Wa -> Wb -> Wa -> Wb (final A in Wb) ----
        const float* src = Wa;
        float* dst = Wb;
        for (int S = 16; S <= 64; S <<= 1) {
            for (int pair = 0; pair < 64 / S; ++pair) {
                const int base = pair * 2 * S;
                const int hb = base + S;
                for (int q = tid; q < S * S; q += 256)
                    co[q] = src[(base + q / S) * NTAG + hb + (q % S)];
                __syncthreads();
                for (int c0 = 0; c0 < 128; c0 += 32) {
                    for (int q = tid; q < S * 32; q += 256)
                        hi[q] = src[(hb + (q >> 5)) * NTAG + c0 + (q & 31)];
                    __syncthreads();
                    for (int q = tid; q < S * 8; q += 256) {
                        const int r = q >> 3;
                        const int c4 = (q & 7) * 4;
                        const int cc = c0 + c4;
                        float4 acc;
                        if (cc >= hb && cc < hb + S)
                            acc = make_float4(0.f, 0.f, 0.f, 0.f);
                        else
                            acc = *reinterpret_cast<const float4*>(
                                &src[(base + r) * NTAG + cc]);
                        for (int t = 0; t < S; ++t) {
                            const float w = co[r * S + t];
                            const float4 h =
                                *reinterpret_cast<const float4*>(&hi[t * 32 + c4]);
                            acc.x = fmaf(w, h.x, acc.x);
                            acc.y = fmaf(w, h.y, acc.y);
                            acc.z = fmaf(w, h.z, acc.z);
                            acc.w = fmaf(w, h.w, acc.w);
                        }
                        *reinterpret_cast<float4*>(&dst[(base + r) * NTAG + cc]) = acc;
                        *reinterpret_cast<float4*>(&dst[(hb + r) * NTAG + cc]) =
                            *reinterpret_cast<const float4*>(&hi[r * 32 + c4]);
                    }
                    __syncthreads();
                }
            }
            const float* ns = dst;
            dst = (dst == Wb) ? Wa : Wb;
            src = ns;
        }
        return;
    }

    // ================= streamer (R8/R15 verbatim) =================
    const int n0 = (blockIdx.x - 1) * TPB;
    {
        const int c = tid >> 5;  // row chunk (16 rows)
        const int n = tid & 31;  // token within block
        int m = -1;
#pragma unroll
        for (int j = 0; j < 16; ++j) {
            const int r = c * 16 + j;
            if (t2t[(size_t)r * NTOK + n0 + n] > 0.f) m = r;
        }
        part[c][n] = m;
    }
    __syncthreads();
    if (tid < TPB) {
        int m = -1;
#pragma unroll
        for (int cc = 0; cc < 8; ++cc) m = max(m, part[cc][tid]);
        tags[tid] = m;
    }
    __syncthreads();

    const int col = tid * 4;
    const float4* src = reinterpret_cast<const float4*>(inp) + (size_t)n0 * 256 + tid;

    float4 acc = make_float4(0.f, 0.f, 0.f, 0.f);
    int cur = tags[0];
    int runlen = 0;

#pragma unroll
    for (int half = 0; half < 2; ++half) {
        float4 v[16];
#pragma unroll
        for (int k = 0; k < 16; ++k)
            v[k] = src[(size_t)(half * 16 + k) * 256];  // 16 loads in flight
#pragma unroll
        for (int k = 0; k < 16; ++k) {
            const int tg = tags[half * 16 + k];
            if (tg != cur) {  // wave-uniform (tags uniform across lanes)
                if (cur >= 0) {
                    float* p = P + (size_t)cur * DDIM + col;
                    atomicAdd(p + 0, acc.x);
                    atomicAdd(p + 1, acc.y);
                    atomicAdd(p + 2, acc.z);
                    atomicAdd(p + 3, acc.w);
                    if (tid == 0) atomicAdd(&cnt[cur], runlen);
                }
                acc = make_float4(0.f, 0.f, 0.f, 0.f);
                cur = tg;
                runlen = 0;
            }
            if (tg >= 0) {
                acc.x += v[k].x;
                acc.y += v[k].y;
                acc.z += v[k].z;
                acc.w += v[k].w;
                ++runlen;
            }
        }
    }
    if (cur >= 0) {
        float* p = P + (size_t)cur * DDIM + col;
        atomicAdd(p + 0, acc.x);
        atomicAdd(p + 1, acc.y);
        atomicAdd(p + 2, acc.z);
        atomicAdd(p + 3, acc.w);
        if (tid == 0) atomicAdd(&cnt[cur], runlen);
    }
}

// ---------------------------------------------------------------------------
// Kernel 2 (k_applyA): out = A * (P/cnt). R12 verbatim (verified). Fully
// parallel 128x128 by 128x1024: 32 blocks; thread = 4x4 register tile; A
// rows stream from L2 (64 KB hot); p staged once per block (16 KB LDS).
// ---------------------------------------------------------------------------
__device__ __forceinline__ void fma4(float4& a, float w, const float4& p) {
    a.x = fmaf(w, p.x, a.x);
    a.y = fmaf(w, p.y, a.y);
    a.z = fmaf(w, p.z, a.z);
    a.w = fmaf(w, p.w, a.w);
}

__global__ __launch_bounds__(256) void k_applyA(const float* __restrict__ P,
                                                const float* __restrict__ A,
                                                const int* __restrict__ cnt,
                                                float* __restrict__ out) {
    __shared__ float pl[NTAG * 32];  // 16 KB
    __shared__ float inv[NTAG];
    const int tid = threadIdx.x;
    const int c0 = blockIdx.x * 32;

    if (tid < NTAG) inv[tid] = 1.0f / (float)cnt[tid];
    __syncthreads();
    for (int q = tid; q < NTAG * 32; q += 256) {
        const int t = q >> 5, c = q & 31;
        pl[q] = P[(size_t)t * DDIM + c0 + c] * inv[t];
    }
    __syncthreads();

    const int i0 = (tid >> 3) * 4;
    const int c4 = (tid & 7) * 4;
    const float* a0 = A + (size_t)(i0 + 0) * NTAG;
    const float* a1 = A + (size_t)(i0 + 1) * NTAG;
    const float* a2 = A + (size_t)(i0 + 2) * NTAG;
    const float* a3 = A + (size_t)(i0 + 3) * NTAG;
    float4 acc0 = make_float4(0.f, 0.f, 0.f, 0.f);
    float4 acc1 = acc0, acc2 = acc0, acc3 = acc0;

#pragma unroll 8
    for (int t = 0; t < NTAG; t += 4) {
        const float4 w0 = *reinterpret_cast<const float4*>(a0 + t);
        const float4 w1 = *reinterpret_cast<const float4*>(a1 + t);
        const float4 w2 = *reinterpret_cast<const float4*>(a2 + t);
        const float4 w3 = *reinterpret_cast<const float4*>(a3 + t);
        const float4 p0 = *reinterpret_cast<const float4*>(&pl[(t + 0) * 32 + c4]);
        const float4 p1 = *reinterpret_cast<const float4*>(&pl[(t + 1) * 32 + c4]);
        const float4 p2 = *reinterpret_cast<const float4*>(&pl[(t + 2) * 32 + c4]);
        const float4 p3 = *reinterpret_cast<const float4*>(&pl[(t + 3) * 32 + c4]);
        fma4(acc0, w0.x, p0); fma4(acc0, w0.y, p1); fma4(acc0, w0.z, p2); fma4(acc0, w0.w, p3);
        fma4(acc1, w1.x, p0); fma4(acc1, w1.y, p1); fma4(acc1, w1.z, p2); fma4(acc1, w1.w, p3);
        fma4(acc2, w2.x, p0); fma4(acc2, w2.y, p1); fma4(acc2, w2.z, p2); fma4(acc2, w2.w, p3);
        fma4(acc3, w3.x, p0); fma4(acc3, w3.y, p1); fma4(acc3, w3.z, p2); fma4(acc3, w3.w, p3);
    }

    *reinterpret_cast<float4*>(out + (size_t)(i0 + 0) * DDIM + c0 + c4) = acc0;
    *reinterpret_cast<float4*>(out + (size_t)(i0 + 1) * DDIM + c0 + c4) = acc1;
    *reinterpret_cast<float4*>(out + (size_t)(i0 + 2) * DDIM + c0 + c4) = acc2;
    *reinterpret_cast<float4*>(out + (size_t)(i0 + 3) * DDIM + c0 + c4) = acc3;
}

// ---------------------------------------------------------------------------
extern "C" void kernel_launch(void* const* d_in, const int* in_sizes, int n_in,
                              void* d_out, int out_size, void* d_ws, size_t ws_size,
                              hipStream_t stream) {
    const float* inp = (const float*)d_in[0];  // (N, D)
    const float* t2t = (const float*)d_in[1];  // (T, N)
    const int* gm = (const int*)d_in[2];       // (T, T)
    float* out = (float*)d_out;                // (T, D)

    char* ws = (char*)d_ws;
    float* P = (float*)ws;                      // 524288 B
    int* cnt = (int*)(ws + 524288);             // 512 B
    float* Wa = (float*)(ws + 524800);          // 65536 B
    float* Wb = (float*)(ws + 524800 + 65536);  // 65536 B

    k_zero<<<128, 256, 0, stream>>>(P, cnt);
    k_fused<<<1 + NTOK / TPB, 256, 0, stream>>>(inp, t2t, P, cnt, gm, Wa, Wb);
    k_applyA<<<32, 256, 0, stream>>>(P, Wb, cnt, out);
}

// Round 17
// 47.086 us; speedup vs baseline: 3.5265x; 3.5265x over previous
//
#include <hip/hip_runtime.h>

// Problem constants (B=1): inputs (N=32768, D=1024) f32, tag_to_token (T=128, N) f32,
// gat_mask (T, T) i32. Output (T, D) f32.
#define NTOK 32768
#define NTAG 128
#define DDIM 1024
#define TPB 64  // tokens per streaming block (R17 A/B: was 32)

// ws layout:
//   P     : 524288 B (unscaled per-tag sums)
//   cnt   : 512 B
//   maskT : 2048 B   (bit-transposed gm for k_recur)

// ---------------------------------------------------------------------------
// Kernel 0 (k_zero): zero P/cnt; blocks 1-2 build the bit-transposed gm mask
// table as a 512-thread gather (verified R8-R15).
// ---------------------------------------------------------------------------
__global__ __launch_bounds__(256) void k_zero(const int* __restrict__ gm,
                                              float* __restrict__ P,
                                              int* __restrict__ cnt,
                                              unsigned* __restrict__ maskT) {
    const int tid = threadIdx.x;
    const int gid = blockIdx.x * 256 + tid;
    reinterpret_cast<float4*>(P)[gid] = make_float4(0.f, 0.f, 0.f, 0.f);
    if (gid < NTAG) cnt[gid] = 0;

    if (blockIdx.x == 1 || blockIdx.x == 2) {
        const int idx = (blockIdx.x - 1) * 256 + tid;  // (k*4+iw)*16+l
        const int l = idx & 15;
        const int iw = (idx >> 4) & 3;
        const int k = idx >> 6;
        const int colg = 16 * k + l;
        unsigned w = 0;
#pragma unroll
        for (int ib = 0; ib < 32; ++ib)
            w |= (unsigned)(gm[(iw * 32 + ib) * NTAG + colg] != 0) << ib;
        maskT[idx] = w;
    }
}

// ---------------------------------------------------------------------------
// Kernel 1 (k_fused): tag-scan + segmented sum. R15-identical EXCEPT TPB=64:
// 512 blocks (8 waves/CU, still >=2x the in-flight bytes needed for HBM
// latency cover), which HALVES the atomicAdd count (~650k) and halves the
// same-address contention (each tag's 256-token span now crosses 4 blocks,
// not 8). Single-variable A/B vs R15's 51.1us to isolate the atomic-
// serialization component of the streamer's ~30us.
//
// Math fact: deduce_direct_string's temp[i][n] is 1 iff i is the LAST
// covering tag of n (for ANY 0/1 coverage), so the row-normalized t2t is
// one-hot per token / cnt[tag] -> the big matmul is a segmented sum into
// P[tag], scaled later by 1/cnt.
// ---------------------------------------------------------------------------
__global__ __launch_bounds__(256, 1) void k_fused(const float* __restrict__ inp,
                                                  const float* __restrict__ t2t,
                                                  float* __restrict__ P,
                                                  int* __restrict__ cnt) {
    __shared__ int part[4][TPB];
    __shared__ int tags[TPB];
    const int tid = threadIdx.x;
    const int n0 = blockIdx.x * TPB;

    // ---- Phase 1: tags for this block's 64 tokens ----
    {
        const int c = tid >> 6;  // row chunk (32 rows)
        const int n = tid & 63;  // token within block
        int m = -1;
#pragma unroll
        for (int j = 0; j < 32; ++j) {
            const int r = c * 32 + j;
            if (t2t[(size_t)r * NTOK + n0 + n] > 0.f) m = r;
        }
        part[c][n] = m;
    }
    __syncthreads();
    if (tid < TPB) {
        int m = -1;
#pragma unroll
        for (int cc = 0; cc < 4; ++cc) m = max(m, part[cc][tid]);
        tags[tid] = m;
    }
    __syncthreads();

    // ---- Phase 2: stream 64 input rows, run-length flush ----
    const int col = tid * 4;
    const float4* src = reinterpret_cast<const float4*>(inp) + (size_t)n0 * 256 + tid;

    float4 acc = make_float4(0.f, 0.f, 0.f, 0.f);
    int cur = tags[0];
    int runlen = 0;

#pragma unroll
    for (int gr = 0; gr < 4; ++gr) {
        float4 v[16];
#pragma unroll
        for (int k = 0; k < 16; ++k)
            v[k] = src[(size_t)(gr * 16 + k) * 256];  // 16 loads in flight
#pragma unroll
        for (int k = 0; k < 16; ++k) {
            const int tg = tags[gr * 16 + k];
            if (tg != cur) {  // wave-uniform (tags uniform across lanes)
                if (cur >= 0) {
                    float* p = P + (size_t)cur * DDIM + col;
                    atomicAdd(p + 0, acc.x);
                    atomicAdd(p + 1, acc.y);
                    atomicAdd(p + 2, acc.z);
                    atomicAdd(p + 3, acc.w);
                    if (tid == 0) atomicAdd(&cnt[cur], runlen);
                }
                acc = make_float4(0.f, 0.f, 0.f, 0.f);
                cur = tg;
                runlen = 0;
            }
            if (tg >= 0) {
                acc.x += v[k].x;
                acc.y += v[k].y;
                acc.z += v[k].z;
                acc.w += v[k].w;
                ++runlen;
            }
        }
    }
    if (cur >= 0) {
        float* p = P + (size_t)cur * DDIM + col;
        atomicAdd(p + 0, acc.x);
        atomicAdd(p + 1, acc.y);
        atomicAdd(p + 2, acc.z);
        atomicAdd(p + 3, acc.w);
        if (tid == 0) atomicAdd(&cnt[cur], runlen);
    }
}

// ---------------------------------------------------------------------------
// Kernel 2 (k_recur): all-register DPP recurrence (verified R8-R15, ~13us).
// deduce_child(gm) == gm for ANY input (reference inner loop provably a
// no-op). One wave = 4 columns (16-lane groups); o in 8 VGPRs; gm bits in
// 32 VGPRs from maskT; per step: 8x shift/and/cvt/fmac + 4 DPP adds + 1
// guarded move; no memory in the loop; ~6KB body.
// ---------------------------------------------------------------------------
template <int CTRL>
__device__ __forceinline__ float dpp_add(float x) {
    const int y = __builtin_amdgcn_update_dpp(0, __float_as_int(x), CTRL, 0xF, 0xF, true);
    return x + __int_as_float(y);
}

__global__ __launch_bounds__(64, 1) void k_recur(const float* __restrict__ P,
                                                 const unsigned* __restrict__ maskT,
                                                 const int* __restrict__ cnt,
                                                 float* __restrict__ out) {
    __shared__ float xpose[NTAG][5];
    const int L = threadIdx.x;
    const int g = L >> 4;
    const int l = L & 15;
    const int c0 = blockIdx.x * 4;

    unsigned mw[8][4];
#pragma unroll
    for (int k = 0; k < 8; ++k)
#pragma unroll
        for (int iw = 0; iw < 4; ++iw) mw[k][iw] = maskT[(k * 4 + iw) * 16 + l];

    const float ia = 1.0f / (float)cnt[L];
    const float ib_ = 1.0f / (float)cnt[64 + L];
    float4 pa = *reinterpret_cast<const float4*>(P + (size_t)L * DDIM + c0);
    float4 pb = *reinterpret_cast<const float4*>(P + (size_t)(64 + L) * DDIM + c0);
    xpose[L][0] = pa.x * ia;
    xpose[L][1] = pa.y * ia;
    xpose[L][2] = pa.z * ia;
    xpose[L][3] = pa.w * ia;
    xpose[64 + L][0] = pb.x * ib_;
    xpose[64 + L][1] = pb.y * ib_;
    xpose[64 + L][2] = pb.z * ib_;
    xpose[64 + L][3] = pb.w * ib_;
    __syncthreads();

    float o0 = xpose[l][g], o1 = xpose[16 + l][g];
    float o2 = xpose[32 + l][g], o3 = xpose[48 + l][g];
    float o4 = xpose[64 + l][g], o5 = xpose[80 + l][g];
    float o6 = xpose[96 + l][g], o7 = xpose[112 + l][g];

#define SECTION(IW, KU, IBHI, IBLO)                                         \
    _Pragma("unroll 2") for (int ib = IBHI; ib >= IBLO; --ib) {             \
        float sa = (float)((mw[0][IW] >> ib) & 1u) * o0;                    \
        sa += (float)((mw[1][IW] >> ib) & 1u) * o1;                         \
        sa += (float)((mw[2][IW] >> ib) & 1u) * o2;                         \
        sa += (float)((mw[3][IW] >> ib) & 1u) * o3;                         \
        float sb = (float)((mw[4][IW] >> ib) & 1u) * o4;                    \
        sb += (float)((mw[5][IW] >> ib) & 1u) * o5;                         \
        sb += (float)((mw[6][IW] >> ib) & 1u) * o6;                         \
        sb += (float)((mw[7][IW] >> ib) & 1u) * o7;                         \
        float s = sa + sb;                                                  \
        s = dpp_add<0xB1>(s);                                               \
        s = dpp_add<0x4E>(s);                                               \
        s = dpp_add<0x141>(s);                                              \
        s = dpp_add<0x140>(s);                                              \
        if (l == (ib & 15)) o##KU = s;                                      \
    }

    SECTION(3, 7, 31, 16)
    SECTION(3, 6, 15, 0)
    SECTION(2, 5, 31, 16)
    SECTION(2, 4, 15, 0)
    SECTION(1, 3, 31, 16)
    SECTION(1, 2, 15, 0)
    SECTION(0, 1, 31, 16)
    SECTION(0, 0, 15, 0)
#undef SECTION

    __syncthreads();
    xpose[l][g] = o0;
    xpose[16 + l][g] = o1;
    xpose[32 + l][g] = o2;
    xpose[48 + l][g] = o3;
    xpose[64 + l][g] = o4;
    xpose[80 + l][g] = o5;
    xpose[96 + l][g] = o6;
    xpose[112 + l][g] = o7;
    __syncthreads();
    float4 ra, rb;
    ra.x = xpose[L][0];
    ra.y = xpose[L][1];
    ra.z = xpose[L][2];
    ra.w = xpose[L][3];
    rb.x = xpose[64 + L][0];
    rb.y = xpose[64 + L][1];
    rb.z = xpose[64 + L][2];
    rb.w = xpose[64 + L][3];
    *reinterpret_cast<float4*>(out + (size_t)L * DDIM + c0) = ra;
    *reinterpret_cast<float4*>(out + (size_t)(64 + L) * DDIM + c0) = rb;
}

// ---------------------------------------------------------------------------
extern "C" void kernel_launch(void* const* d_in, const int* in_sizes, int n_in,
                              void* d_out, int out_size, void* d_ws, size_t ws_size,
                              hipStream_t stream) {
    const float* inp = (const float*)d_in[0];  // (N, D)
    const float* t2t = (const float*)d_in[1];  // (T, N)
    const int* gm = (const int*)d_in[2];       // (T, T)
    float* out = (float*)d_out;                // (T, D)

    char* ws = (char*)d_ws;
    float* P = (float*)ws;                       // 524288 B
    int* cnt = (int*)(ws + 524288);              // 512 B
    unsigned* maskT = (unsigned*)(ws + 524800);  // 2048 B

    k_zero<<<128, 256, 0, stream>>>(gm, P, cnt, maskT);
    k_fused<<<NTOK / TPB, 256, 0, stream>>>(inp, t2t, P, cnt);
    k_recur<<<DDIM / 4, 64, 0, stream>>>(P, maskT, cnt, out);
}

// Round 18
// 45.987 us; speedup vs baseline: 3.6109x; 1.0239x over previous
//
#include <hip/hip_runtime.h>

// Problem constants (B=1): inputs (N=32768, D=1024) f32, tag_to_token (T=128, N) f32,
// gat_mask (T, T) i32. Output (T, D) f32.
#define NTOK 32768
#define NTAG 128
#define DDIM 1024
#define TPB 128  // tokens per streaming block (R18 A/B: 32->64 gave -4.0us; now 64->128)

// ws layout:
//   P     : 524288 B (unscaled per-tag sums)
//   cnt   : 512 B
//   maskT : 2048 B   (bit-transposed gm for k_recur)

// ---------------------------------------------------------------------------
// Kernel 0 (k_zero): zero P/cnt; blocks 1-2 build the bit-transposed gm mask
// table as a 512-thread gather (verified R8-R17).
// ---------------------------------------------------------------------------
__global__ __launch_bounds__(256) void k_zero(const int* __restrict__ gm,
                                              float* __restrict__ P,
                                              int* __restrict__ cnt,
                                              unsigned* __restrict__ maskT) {
    const int tid = threadIdx.x;
    const int gid = blockIdx.x * 256 + tid;
    reinterpret_cast<float4*>(P)[gid] = make_float4(0.f, 0.f, 0.f, 0.f);
    if (gid < NTAG) cnt[gid] = 0;

    if (blockIdx.x == 1 || blockIdx.x == 2) {
        const int idx = (blockIdx.x - 1) * 256 + tid;  // (k*4+iw)*16+l
        const int l = idx & 15;
        const int iw = (idx >> 4) & 3;
        const int k = idx >> 6;
        const int colg = 16 * k + l;
        unsigned w = 0;
#pragma unroll
        for (int ib = 0; ib < 32; ++ib)
            w |= (unsigned)(gm[(iw * 32 + ib) * NTAG + colg] != 0) << ib;
        maskT[idx] = w;
    }
}

// ---------------------------------------------------------------------------
// Kernel 1 (k_fused): tag-scan + segmented sum. R17-identical EXCEPT TPB=128:
// grid 256 = exactly 1 block/CU (4 waves; 64KB in-flight per CU >> the ~22KB
// needed to cover HBM latency at per-CU BW share). Atomic dwords halve again
// (~390k) and each 256-token tag span now crosses at most 2 blocks (2-way
// same-address overlap, was 4). R17's A/B (TPB 32->64: -4.0us) confirmed
// atomic contention is a real component of the streamer cost.
//
// Math fact: deduce_direct_string's temp[i][n] is 1 iff i is the LAST
// covering tag of n (for ANY 0/1 coverage), so the row-normalized t2t is
// one-hot per token / cnt[tag] -> the big matmul is a segmented sum into
// P[tag], scaled later by 1/cnt.
// ---------------------------------------------------------------------------
__global__ __launch_bounds__(256, 1) void k_fused(const float* __restrict__ inp,
                                                  const float* __restrict__ t2t,
                                                  float* __restrict__ P,
                                                  int* __restrict__ cnt) {
    __shared__ int part[2][TPB];
    __shared__ int tags[TPB];
    const int tid = threadIdx.x;
    const int n0 = blockIdx.x * TPB;

    // ---- Phase 1: tags for this block's 128 tokens ----
    {
        const int c = tid >> 7;  // row chunk (64 rows)
        const int n = tid & 127; // token within block
        int m = -1;
#pragma unroll
        for (int j = 0; j < 64; ++j) {
            const int r = c * 64 + j;
            if (t2t[(size_t)r * NTOK + n0 + n] > 0.f) m = r;
        }
        part[c][n] = m;
    }
    __syncthreads();
    if (tid < TPB) tags[tid] = max(part[0][tid], part[1][tid]);
    __syncthreads();

    // ---- Phase 2: stream 128 input rows, run-length flush ----
    const int col = tid * 4;
    const float4* src = reinterpret_cast<const float4*>(inp) + (size_t)n0 * 256 + tid;

    float4 acc = make_float4(0.f, 0.f, 0.f, 0.f);
    int cur = tags[0];
    int runlen = 0;

#pragma unroll
    for (int gr = 0; gr < 8; ++gr) {
        float4 v[16];
#pragma unroll
        for (int k = 0; k < 16; ++k)
            v[k] = src[(size_t)(gr * 16 + k) * 256];  // 16 loads in flight
#pragma unroll
        for (int k = 0; k < 16; ++k) {
            const int tg = tags[gr * 16 + k];
            if (tg != cur) {  // wave-uniform (tags uniform across lanes)
                if (cur >= 0) {
                    float* p = P + (size_t)cur * DDIM + col;
                    atomicAdd(p + 0, acc.x);
                    atomicAdd(p + 1, acc.y);
                    atomicAdd(p + 2, acc.z);
                    atomicAdd(p + 3, acc.w);
                    if (tid == 0) atomicAdd(&cnt[cur], runlen);
                }
                acc = make_float4(0.f, 0.f, 0.f, 0.f);
                cur = tg;
                runlen = 0;
            }
            if (tg >= 0) {
                acc.x += v[k].x;
                acc.y += v[k].y;
                acc.z += v[k].z;
                acc.w += v[k].w;
                ++runlen;
            }
        }
    }
    if (cur >= 0) {
        float* p = P + (size_t)cur * DDIM + col;
        atomicAdd(p + 0, acc.x);
        atomicAdd(p + 1, acc.y);
        atomicAdd(p + 2, acc.z);
        atomicAdd(p + 3, acc.w);
        if (tid == 0) atomicAdd(&cnt[cur], runlen);
    }
}

// ---------------------------------------------------------------------------
// Kernel 2 (k_recur): all-register DPP recurrence (verified R8-R17).
// deduce_child(gm) == gm for ANY input (reference inner loop provably a
// no-op). One wave = 4 columns (16-lane groups); o in 8 VGPRs; gm bits in
// 32 VGPRs from maskT; per step: 8x shift/and/cvt/fmac + 4 DPP adds + 1
// guarded move; no memory in the loop; ~6KB body.
// ---------------------------------------------------------------------------
template <int CTRL>
__device__ __forceinline__ float dpp_add(float x) {
    const int y = __builtin_amdgcn_update_dpp(0, __float_as_int(x), CTRL, 0xF, 0xF, true);
    return x + __int_as_float(y);
}

__global__ __launch_bounds__(64, 1) void k_recur(const float* __restrict__ P,
                                                 const unsigned* __restrict__ maskT,
                                                 const int* __restrict__ cnt,
                                                 float* __restrict__ out) {
    __shared__ float xpose[NTAG][5];
    const int L = threadIdx.x;
    const int g = L >> 4;
    const int l = L & 15;
    const int c0 = blockIdx.x * 4;

    unsigned mw[8][4];
#pragma unroll
    for (int k = 0; k < 8; ++k)
#pragma unroll
        for (int iw = 0; iw < 4; ++iw) mw[k][iw] = maskT[(k * 4 + iw) * 16 + l];

    const float ia = 1.0f / (float)cnt[L];
    const float ib_ = 1.0f / (float)cnt[64 + L];
    float4 pa = *reinterpret_cast<const float4*>(P + (size_t)L * DDIM + c0);
    float4 pb = *reinterpret_cast<const float4*>(P + (size_t)(64 + L) * DDIM + c0);
    xpose[L][0] = pa.x * ia;
    xpose[L][1] = pa.y * ia;
    xpose[L][2] = pa.z * ia;
    xpose[L][3] = pa.w * ia;
    xpose[64 + L][0] = pb.x * ib_;
    xpose[64 + L][1] = pb.y * ib_;
    xpose[64 + L][2] = pb.z * ib_;
    xpose[64 + L][3] = pb.w * ib_;
    __syncthreads();

    float o0 = xpose[l][g], o1 = xpose[16 + l][g];
    float o2 = xpose[32 + l][g], o3 = xpose[48 + l][g];
    float o4 = xpose[64 + l][g], o5 = xpose[80 + l][g];
    float o6 = xpose[96 + l][g], o7 = xpose[112 + l][g];

#define SECTION(IW, KU, IBHI, IBLO)                                         \
    _Pragma("unroll 2") for (int ib = IBHI; ib >= IBLO; --ib) {             \
        float sa = (float)((mw[0][IW] >> ib) & 1u) * o0;                    \
        sa += (float)((mw[1][IW] >> ib) & 1u) * o1;                         \
        sa += (float)((mw[2][IW] >> ib) & 1u) * o2;                         \
        sa += (float)((mw[3][IW] >> ib) & 1u) * o3;                         \
        float sb = (float)((mw[4][IW] >> ib) & 1u) * o4;                    \
        sb += (float)((mw[5][IW] >> ib) & 1u) * o5;                         \
        sb += (float)((mw[6][IW] >> ib) & 1u) * o6;                         \
        sb += (float)((mw[7][IW] >> ib) & 1u) * o7;                         \
        float s = sa + sb;                                                  \
        s = dpp_add<0xB1>(s);                                               \
        s = dpp_add<0x4E>(s);                                               \
        s = dpp_add<0x141>(s);                                              \
        s = dpp_add<0x140>(s);                                              \
        if (l == (ib & 15)) o##KU = s;                                      \
    }

    SECTION(3, 7, 31, 16)
    SECTION(3, 6, 15, 0)
    SECTION(2, 5, 31, 16)
    SECTION(2, 4, 15, 0)
    SECTION(1, 3, 31, 16)
    SECTION(1, 2, 15, 0)
    SECTION(0, 1, 31, 16)
    SECTION(0, 0, 15, 0)
#undef SECTION

    __syncthreads();
    xpose[l][g] = o0;
    xpose[16 + l][g] = o1;
    xpose[32 + l][g] = o2;
    xpose[48 + l][g] = o3;
    xpose[64 + l][g] = o4;
    xpose[80 + l][g] = o5;
    xpose[96 + l][g] = o6;
    xpose[112 + l][g] = o7;
    __syncthreads();
    float4 ra, rb;
    ra.x = xpose[L][0];
    ra.y = xpose[L][1];
    ra.z = xpose[L][2];
    ra.w = xpose[L][3];
    rb.x = xpose[64 + L][0];
    rb.y = xpose[64 + L][1];
    rb.z = xpose[64 + L][2];
    rb.w = xpose[64 + L][3];
    *reinterpret_cast<float4*>(out + (size_t)L * DDIM + c0) = ra;
    *reinterpret_cast<float4*>(out + (size_t)(64 + L) * DDIM + c0) = rb;
}

// ---------------------------------------------------------------------------
extern "C" void kernel_launch(void* const* d_in, const int* in_sizes, int n_in,
                              void* d_out, int out_size, void* d_ws, size_t ws_size,
                              hipStream_t stream) {
    const float* inp = (const float*)d_in[0];  // (N, D)
    const float* t2t = (const float*)d_in[1];  // (T, N)
    const int* gm = (const int*)d_in[2];       // (T, T)
    float* out = (float*)d_out;                // (T, D)

    char* ws = (char*)d_ws;
    float* P = (float*)ws;                       // 524288 B
    int* cnt = (int*)(ws + 524288);              // 512 B
    unsigned* maskT = (unsigned*)(ws + 524800);  // 2048 B

    k_zero<<<128, 256, 0, stream>>>(gm, P, cnt, maskT);
    k_fused<<<NTOK / TPB, 256, 0, stream>>>(inp, t2t, P, cnt);
    k_recur<<<DDIM / 4, 64, 0, stream>>>(P, maskT, cnt, out);
}